// Round 6
// baseline (1208.502 us; speedup 1.0000x reference)
//
#include <hip/hip_runtime.h>
#include <hip/hip_bf16.h>
#include <stdint.h>

#define NN 8192
#define DD 512

typedef unsigned short u16;
typedef __attribute__((ext_vector_type(8))) short short8;
typedef __attribute__((ext_vector_type(4))) float f32x4;

// async global->LDS, 16B per lane; LDS dest = wave-uniform base + lane*16
__device__ __forceinline__ void gld_lds16(const void* g, void* l) {
  __builtin_amdgcn_global_load_lds(
      (const __attribute__((address_space(1))) uint32_t*)(uintptr_t)g,
      (__attribute__((address_space(3))) uint32_t*)(uintptr_t)l,
      16, 0, 0);
}

__device__ __forceinline__ u16 f2bf(float f) {
  __hip_bfloat16 b = __float2bfloat16(f);
  return __builtin_bit_cast(u16, b);
}

__global__ void fill_kernel(float* __restrict__ p, int n, float v) {
  int i = blockIdx.x * 256 + threadIdx.x;
  int stride = gridDim.x * 256;
  for (; i < n; i += stride) p[i] = v;
}

__global__ void cvt4_kernel(const float4* __restrict__ src, ushort4* __restrict__ dst, int n4) {
  int i = blockIdx.x * 256 + threadIdx.x;
  int stride = gridDim.x * 256;
  for (; i < n4; i += stride) {
    float4 v = src[i];
    ushort4 o;
    o.x = f2bf(v.x); o.y = f2bf(v.y); o.z = f2bf(v.z); o.w = f2bf(v.w);
    dst[i] = o;
  }
}

// one wave per row: 1/||Wh_i||; also zeroes den[row]
__global__ void rownorm_kernel(const float* __restrict__ Wh, float* __restrict__ invn,
                               float* __restrict__ den) {
  int row = blockIdx.x;
  int l = threadIdx.x;  // 64
  const float4* p = (const float4*)(Wh + (size_t)row * DD);
  float4 a = p[l], b = p[l + 64];
  float s = a.x*a.x + a.y*a.y + a.z*a.z + a.w*a.w
          + b.x*b.x + b.y*b.y + b.z*b.z + b.w*b.w;
  #pragma unroll
  for (int off = 32; off; off >>= 1) s += __shfl_down(s, off);
  if (l == 0) {
    invn[row] = 1.0f / sqrtf(s);
    den[row] = 0.0f;
  }
}

// 64x64 tile: U = bf16(Wh * invn) (row-major) and WhT = bf16(Wh)^T
__global__ void u_wht_kernel(const float* __restrict__ Wh, const float* __restrict__ invn,
                             u16* __restrict__ U, u16* __restrict__ WhT) {
  __shared__ float tile[64][65];
  int i0 = blockIdx.x * 64, d0 = blockIdx.y * 64;
  int c = threadIdx.x & 63, rb = threadIdx.x >> 6;
  #pragma unroll
  for (int r = rb; r < 64; r += 4) {
    float v = Wh[(size_t)(i0 + r) * DD + d0 + c];
    tile[r][c] = v;
    U[(size_t)(i0 + r) * DD + d0 + c] = f2bf(v * invn[i0 + r]);
  }
  __syncthreads();
  #pragma unroll
  for (int r = rb; r < 64; r += 4) {
    WhT[(size_t)(d0 + r) * NN + i0 + c] = f2bf(tile[c][r]);
  }
}

// Wh-GEMM: C = A * B^T fp32, A:[M x K], B:[Nn x K] bf16. 128x128 tile, 256 thr.
__global__ void __launch_bounds__(256) gemm_wh(
    const u16* __restrict__ A, const u16* __restrict__ B,
    int Nn, int K, float* __restrict__ Cf)
{
  __shared__ __align__(16) u16 As[128 * 32];
  __shared__ __align__(16) u16 Bs[128 * 32];

  const int tid = threadIdx.x;
  const int w = tid >> 6;
  const int lane = tid & 63;
  const int lm = lane & 15;
  const int q = lane >> 4;
  const int row0 = blockIdx.y * 128;
  const int col0 = blockIdx.x * 128;
  const int RM = (w >> 1) * 64;
  const int RN = (w & 1) * 64;
  const int sr = tid >> 2;
  const int sk = (tid & 3) * 8;

  f32x4 acc[4][4];
  #pragma unroll
  for (int a_ = 0; a_ < 4; a_++)
    #pragma unroll
    for (int b_ = 0; b_ < 4; b_++)
      acc[a_][b_] = (f32x4){0.f, 0.f, 0.f, 0.f};

  const size_t Abase = (size_t)row0 * K;
  const size_t Bbase = (size_t)col0 * K;

  for (int k0 = 0; k0 < K; k0 += 32) {
    __syncthreads();
    gld_lds16(A + Abase + (size_t)sr * K + k0 + sk,        (char*)As + w * 1024);
    gld_lds16(A + Abase + (size_t)(sr + 64) * K + k0 + sk, (char*)As + 4096 + w * 1024);
    gld_lds16(B + Bbase + (size_t)sr * K + k0 + sk,        (char*)Bs + w * 1024);
    gld_lds16(B + Bbase + (size_t)(sr + 64) * K + k0 + sk, (char*)Bs + 4096 + w * 1024);
    __syncthreads();

    short8 af[4], bfr[4];
    #pragma unroll
    for (int mt = 0; mt < 4; mt++)
      af[mt] = *(const short8*)&As[(RM + mt * 16 + lm) * 32 + q * 8];
    #pragma unroll
    for (int nt = 0; nt < 4; nt++)
      bfr[nt] = *(const short8*)&Bs[(RN + nt * 16 + lm) * 32 + q * 8];

    #pragma unroll
    for (int mt = 0; mt < 4; mt++)
      #pragma unroll
      for (int nt = 0; nt < 4; nt++)
        acc[mt][nt] = __builtin_amdgcn_mfma_f32_16x16x32_bf16(af[mt], bfr[nt], acc[mt][nt], 0, 0, 0);
  }

  #pragma unroll
  for (int mt = 0; mt < 4; mt++) {
    const int ib = row0 + RM + mt * 16 + q * 4;
    #pragma unroll
    for (int rr = 0; rr < 4; rr++) {
      const int i = ib + rr;
      #pragma unroll
      for (int nt = 0; nt < 4; nt++) {
        const int jc = col0 + RN + nt * 16 + lm;
        Cf[(size_t)i * Nn + jc] = acc[mt][nt][rr];
      }
    }
  }
}

// ---------------------------------------------------------------------------
// flash: fused sim+out. Per block: 64 i-rows x one j-half (4096 j, 32 tiles of
// 128). S = Q @ Uj^T with Q IN REGISTERS (128 VGPR); exp+adj-mask -> P bf16 in
// LDS (never HBM); out-acc += P @ WhT^T in fp32 regs; den via atomics.
// Eliminates: P 134 MB write + 268 MB read, gemm_out2, reduce4's bf16 partials.
// Schedule: 8-step ring per tile {S0 S1 S2 S3 | E | P0 P1 P2 P3}, each step
// stages the buffer it just consumed for step+2 (proven lgkm0+barrier safety),
// counted vmcnt(4) (vmcnt(20) at P3 where 16 adj loads sit mid-queue; adj
// issued at P2 post-vmcnt -> 3-step lead). 144 KB LDS, 1 block/CU, 8 waves
// = 2 row-groups x 4 (j-slices in S/E, d-slices in PV).
// ---------------------------------------------------------------------------
__global__ void __launch_bounds__(512, 2) flash(
    const u16* __restrict__ U,    // [NN][DD] normalized bf16
    const u16* __restrict__ Wt,   // [DD][NN] Wh^T bf16
    const int* __restrict__ adj,
    float* __restrict__ accH,     // [2][NN][DD] fp32 partials
    float* __restrict__ den)
{
  // KV0/KV1: Uj k-slices [128 j][128 k] bf16 = 32 KB each
  // WT0/WT1: WhT j-slices [512 d][32 j] bf16 = 32 KB each
  // P:       [64 i][128 j] bf16 = 16 KB
  __shared__ __align__(16) char lds[147456];
  constexpr int KV0 = 0, KV1 = 32768, WT0 = 65536, WT1 = 98304, POFF = 131072;

  const int tid = threadIdx.x;
  const int w = tid >> 6;
  const int lane = tid & 63;
  const int lm = lane & 15;
  const int q = lane >> 4;
  const int rg = w >> 2;            // 0/1: 32-row group
  const int xg = w & 3;             // S/E: 32-j slice; PV: 128-d slice
  const int jh = blockIdx.x;        // j-half
  const int i0 = blockIdx.y * 64;
  const int jb = jh * (NN / 2);
  float* accP = accH + (size_t)jh * NN * DD;

  // staging (both-sides XOR swizzle; LDS dest linear per gld_lds semantics)
  const int kvrow = tid >> 4;                                    // 0..31
  const int kvsrc = ((tid & 15) ^ (((tid >> 4) & 7) << 1)) * 8;  // u16 elems
  const int wtrow = tid >> 2;                                    // 0..127
  const int wtsrc = ((tid & 3) ^ ((tid >> 3) & 3)) * 8;
  const int sdst = w << 10;
  // read-side swizzle keys
  const int sk_x = (lm & 7) << 1;                        // 256B rows (KV, P)
  const int wq_x = (q ^ ((lm >> 1) & 3)) << 4;           // 64B rows (WT)

  f32x4 acc_s0[2], acc_s1[2], acc_o0[8], acc_o1[8];
  #pragma unroll
  for (int n = 0; n < 2; n++) { acc_s0[n] = (f32x4){0.f,0.f,0.f,0.f}; acc_s1[n] = (f32x4){0.f,0.f,0.f,0.f}; }
  #pragma unroll
  for (int n = 0; n < 8; n++) { acc_o0[n] = (f32x4){0.f,0.f,0.f,0.f}; acc_o1[n] = (f32x4){0.f,0.f,0.f,0.f}; }
  float dacc0[4] = {0.f,0.f,0.f,0.f}, dacc1[4] = {0.f,0.f,0.f,0.f};
  int na0[2][4], na1[2][4];

  // Q fragments in registers: rows i0 + rg*32 + {0,16} + lm, all K=512
  short8 Qf0[16], Qf1[16];
  {
    const u16* q0 = U + (size_t)(i0 + rg * 32 + lm) * DD + q * 8;
    const u16* q1 = q0 + 16 * DD;
    #pragma unroll
    for (int ks = 0; ks < 16; ks++) {
      Qf0[ks] = *(const short8*)(q0 + ks * 32);
      Qf1[ks] = *(const short8*)(q1 + ks * 32);
    }
  }
  asm volatile("" ::: "memory");  // pin issue order for vmcnt accounting

#define ADJ_LOAD(T_) do {                                                         \
    const int* ap_ = adj + (size_t)(i0 + rg * 32 + q * 4) * NN + jb               \
                     + (size_t)(T_) * 128 + xg * 32 + lm;                         \
    _Pragma("unroll")                                                             \
    for (int rr_ = 0; rr_ < 4; rr_++) {                                           \
      na0[0][rr_] = ap_[(size_t)rr_ * NN];                                        \
      na0[1][rr_] = ap_[(size_t)rr_ * NN + 16];                                   \
      na1[0][rr_] = ap_[(size_t)(16 + rr_) * NN];                                 \
      na1[1][rr_] = ap_[(size_t)(16 + rr_) * NN + 16];                            \
    }                                                                             \
  } while (0)

#define STG_KV(T_, k0_, buf_) do {                                                \
    const u16* s_ = U + (size_t)(jb + (T_) * 128 + kvrow) * DD + (k0_) + kvsrc;   \
    gld_lds16(s_,             lds + (buf_) + sdst);                               \
    gld_lds16(s_ + 32 * DD,   lds + (buf_) + 8192 + sdst);                        \
    gld_lds16(s_ + 64 * DD,   lds + (buf_) + 16384 + sdst);                       \
    gld_lds16(s_ + 96 * DD,   lds + (buf_) + 24576 + sdst);                       \
  } while (0)

#define STG_WT(T_, j2_, buf_) do {                                                \
    const u16* s_ = Wt + (size_t)wtrow * NN + jb + (T_) * 128 + (j2_) * 32 + wtsrc; \
    gld_lds16(s_,              lds + (buf_) + sdst);                              \
    gld_lds16(s_ + 128 * NN,   lds + (buf_) + 8192 + sdst);                       \
    gld_lds16(s_ + 256 * NN,   lds + (buf_) + 16384 + sdst);                      \
    gld_lds16(s_ + 384 * NN,   lds + (buf_) + 24576 + sdst);                      \
  } while (0)

  // prologue: adj tile0; KV slices 0,1; drain all but KV1's 4
  ADJ_LOAD(0);
  asm volatile("" ::: "memory");
  STG_KV(0, 0, KV0);
  STG_KV(0, 128, KV1);
  asm volatile("s_waitcnt vmcnt(4)" ::: "memory");
  asm volatile("s_barrier" ::: "memory");

#define SSTEP(s_, buf_, STAGE_STMT, VMC) do {                                     \
    short8 bn0_[4], bn1_[4];                                                      \
    const char* cb_ = lds + (buf_);                                               \
    _Pragma("unroll")                                                             \
    for (int ks_ = 0; ks_ < 4; ks_++) {                                           \
      bn0_[ks_] = *(const short8*)(cb_ + (xg * 32 + lm) * 256 + (((ks_ * 4 + q) ^ sk_x) << 4)); \
      bn1_[ks_] = *(const short8*)(cb_ + (xg * 32 + 16 + lm) * 256 + (((ks_ * 4 + q) ^ sk_x) << 4)); \
    }                                                                             \
    asm volatile("s_barrier" ::: "memory");                                       \
    asm volatile("s_waitcnt lgkmcnt(0)" ::: "memory");                            \
    __builtin_amdgcn_s_setprio(1);                                                \
    _Pragma("unroll")                                                             \
    for (int ks_ = 0; ks_ < 4; ks_++) {                                           \
      acc_s0[0] = __builtin_amdgcn_mfma_f32_16x16x32_bf16(Qf0[(s_) * 4 + ks_], bn0_[ks_], acc_s0[0], 0, 0, 0); \
      acc_s0[1] = __builtin_amdgcn_mfma_f32_16x16x32_bf16(Qf0[(s_) * 4 + ks_], bn1_[ks_], acc_s0[1], 0, 0, 0); \
      acc_s1[0] = __builtin_amdgcn_mfma_f32_16x16x32_bf16(Qf1[(s_) * 4 + ks_], bn0_[ks_], acc_s1[0], 0, 0, 0); \
      acc_s1[1] = __builtin_amdgcn_mfma_f32_16x16x32_bf16(Qf1[(s_) * 4 + ks_], bn1_[ks_], acc_s1[1], 0, 0, 0); \
    }                                                                             \
    __builtin_amdgcn_s_setprio(0);                                                \
    asm volatile("s_barrier" ::: "memory");                                       \
    STAGE_STMT;                                                                   \
    asm volatile("s_waitcnt " VMC ::: "memory");                                  \
    asm volatile("s_barrier" ::: "memory");                                       \
  } while (0)

#define PSTEP(p_, buf_, STAGE_STMT, POST_STMT, VMC) do {                          \
    short8 pa0_, pa1_, wb_[8];                                                    \
    pa0_ = *(const short8*)(lds + POFF + (rg * 32 + lm) * 256 + ((((p_) * 4 + q) ^ sk_x) << 4)); \
    pa1_ = *(const short8*)(lds + POFF + (rg * 32 + 16 + lm) * 256 + ((((p_) * 4 + q) ^ sk_x) << 4)); \
    const char* wbb_ = lds + (buf_);                                              \
    _Pragma("unroll")                                                             \
    for (int nt_ = 0; nt_ < 8; nt_++)                                             \
      wb_[nt_] = *(const short8*)(wbb_ + (xg * 128 + nt_ * 16 + lm) * 64 + wq_x); \
    asm volatile("s_barrier" ::: "memory");                                       \
    asm volatile("s_waitcnt lgkmcnt(0)" ::: "memory");                            \
    __builtin_amdgcn_s_setprio(1);                                                \
    _Pragma("unroll")                                                             \
    for (int nt_ = 0; nt_ < 8; nt_++) {                                           \
      acc_o0[nt_] = __builtin_amdgcn_mfma_f32_16x16x32_bf16(pa0_, wb_[nt_], acc_o0[nt_], 0, 0, 0); \
      acc_o1[nt_] = __builtin_amdgcn_mfma_f32_16x16x32_bf16(pa1_, wb_[nt_], acc_o1[nt_], 0, 0, 0); \
    }                                                                             \
    __builtin_amdgcn_s_setprio(0);                                                \
    asm volatile("s_barrier" ::: "memory");                                       \
    STAGE_STMT;                                                                   \
    asm volatile("s_waitcnt " VMC ::: "memory");                                  \
    POST_STMT;                                                                    \
    asm volatile("s_barrier" ::: "memory");                                       \
  } while (0)

#define ESTEP(T_) do {                                                            \
    _Pragma("unroll")                                                             \
    for (int nt_ = 0; nt_ < 2; nt_++) {                                           \
      _Pragma("unroll")                                                           \
      for (int rr_ = 0; rr_ < 4; rr_++) {                                         \
        const int col_ = xg * 32 + nt_ * 16 + lm;                                 \
        const int jc_ = jb + (T_) * 128 + col_;                                   \
        {                                                                         \
          const int i_ = i0 + rg * 32 + q * 4 + rr_;                              \
          const float ev_ = __expf(acc_s0[nt_][rr_]);                             \
          const float p_ = (na0[nt_][rr_] != 0 || i_ == jc_) ? ev_ : 0.0f;        \
          dacc0[rr_] += p_;                                                       \
          const int rp_ = rg * 32 + q * 4 + rr_;                                  \
          *(u16*)(lds + POFF + rp_ * 256 + ((((col_ >> 3) ^ ((rp_ & 7) << 1)) << 4)) + (col_ & 7) * 2) = f2bf(p_); \
        }                                                                         \
        {                                                                         \
          const int i_ = i0 + rg * 32 + 16 + q * 4 + rr_;                         \
          const float ev_ = __expf(acc_s1[nt_][rr_]);                             \
          const float p_ = (na1[nt_][rr_] != 0 || i_ == jc_) ? ev_ : 0.0f;        \
          dacc1[rr_] += p_;                                                       \
          const int rp_ = rg * 32 + 16 + q * 4 + rr_;                             \
          *(u16*)(lds + POFF + rp_ * 256 + ((((col_ >> 3) ^ ((rp_ & 7) << 1)) << 4)) + (col_ & 7) * 2) = f2bf(p_); \
        }                                                                         \
      }                                                                           \
      acc_s0[nt_] = (f32x4){0.f, 0.f, 0.f, 0.f};                                  \
      acc_s1[nt_] = (f32x4){0.f, 0.f, 0.f, 0.f};                                  \
    }                                                                             \
    asm volatile("s_waitcnt lgkmcnt(0)" ::: "memory");                            \
    asm volatile("s_barrier" ::: "memory");                                       \
  } while (0)

  #pragma unroll 1
  for (int T = 0; T < 32; T++) {
    SSTEP(0, KV0, STG_KV(T, 256, KV0), "vmcnt(4)");
    SSTEP(1, KV1, STG_KV(T, 384, KV1), "vmcnt(4)");
    SSTEP(2, KV0, STG_WT(T, 0, WT0), "vmcnt(4)");
    SSTEP(3, KV1, STG_WT(T, 1, WT1), "vmcnt(4)");
    ESTEP(T);
    PSTEP(0, WT0, STG_WT(T, 2, WT0), {}, "vmcnt(4)");
    PSTEP(1, WT1, STG_WT(T, 3, WT1), {}, "vmcnt(4)");
    if (T < 31) {
      PSTEP(2, WT0, STG_KV(T + 1, 0, KV0), ADJ_LOAD(T + 1), "vmcnt(4)");
      PSTEP(3, WT1, STG_KV(T + 1, 128, KV1), {}, "vmcnt(20)");
    } else {
      PSTEP(2, WT0, {}, {}, "vmcnt(0)");
      PSTEP(3, WT1, {}, {}, "vmcnt(0)");
    }
  }
#undef SSTEP
#undef PSTEP
#undef ESTEP
#undef STG_KV
#undef STG_WT
#undef ADJ_LOAD

  // den: reduce over 16 lanes (this wave's j-slice partial), atomic per row
  #pragma unroll
  for (int rr = 0; rr < 4; rr++) {
    float s0 = dacc0[rr], s1 = dacc1[rr];
    #pragma unroll
    for (int off = 8; off; off >>= 1) {
      s0 += __shfl_down(s0, off, 16);
      s1 += __shfl_down(s1, off, 16);
    }
    if (lm == 0) {
      atomicAdd(&den[i0 + rg * 32 + q * 4 + rr], s0);
      atomicAdd(&den[i0 + rg * 32 + 16 + q * 4 + rr], s1);
    }
  }
  // fp32 partial stores (each (i,d) written by exactly one wave)
  #pragma unroll
  for (int nt = 0; nt < 8; nt++) {
    #pragma unroll
    for (int rr = 0; rr < 4; rr++) {
      accP[(size_t)(i0 + rg * 32 + q * 4 + rr) * DD + xg * 128 + nt * 16 + lm] = acc_o0[nt][rr];
      accP[(size_t)(i0 + rg * 32 + 16 + q * 4 + rr) * DD + xg * 128 + nt * 16 + lm] = acc_o1[nt][rr];
    }
  }
}

// out = (acc0 + acc1) / den[row], fp32 partials
__global__ void reduce2_kernel(const float4* __restrict__ a0, const float4* __restrict__ a1,
                               const float* __restrict__ den, float4* __restrict__ out) {
  const int idx = blockIdx.x * 256 + threadIdx.x;  // NN*DD/4 float4 units
  const int row = idx >> 7;                        // DD/4 = 128 per row
  const float dinv = 1.0f / den[row];
  float4 x = a0[idx], y = a1[idx];
  float4 o = {(x.x + y.x) * dinv, (x.y + y.y) * dinv, (x.z + y.z) * dinv, (x.w + y.w) * dinv};
  out[idx] = o;
}

extern "C" void kernel_launch(void* const* d_in, const int* in_sizes, int n_in,
                              void* d_out, int out_size, void* d_ws, size_t ws_size,
                              hipStream_t stream) {
  const float* h = (const float*)d_in[0];
  const int* adj = (const int*)d_in[1];
  const float* W = (const float*)d_in[2];
  float* out = (float*)d_out;

  const size_t SZ_ACC = (size_t)2 * NN * DD * 4;   // 33.6 MB (fp32 x2; prefix aliases Wh fp32)
  const size_t SZ_WHT = (size_t)DD * NN * 2;       // 8.4 MB
  const size_t SZ_HB  = (size_t)NN * DD * 2;       // 8.4 MB
  const size_t SZ_WB  = (size_t)DD * DD * 2;       // 0.5 MB
  const size_t SZ_U   = (size_t)NN * DD * 2;       // 8.4 MB
  const size_t NEEDED = SZ_ACC + SZ_WHT + SZ_HB + SZ_WB + SZ_U + 2 * (size_t)NN * 4;

  if (ws_size < NEEDED) {
    fill_kernel<<<256, 256, 0, stream>>>(out, out_size, 12345.0f);
    return;
  }

  char* ws = (char*)d_ws;
  size_t off = 0;
  float* acc0 = (float*)(ws + off); off += SZ_ACC;   // acc1 = acc0 + NN*DD
  u16*   WhT  = (u16*)(ws + off); off += SZ_WHT;
  u16*   hb   = (u16*)(ws + off); off += SZ_HB;
  u16*   Wb   = (u16*)(ws + off); off += SZ_WB;
  u16*   U    = (u16*)(ws + off); off += SZ_U;
  float* invn = (float*)(ws + off);
  float* den  = invn + NN;

  // Wh fp32 (16.8 MB) aliases the acc prefix: dead before flash writes acc.
  float* Wh = acc0;
  float* acc1 = acc0 + (size_t)NN * DD;

  cvt4_kernel<<<1024, 256, 0, stream>>>((const float4*)h, (ushort4*)hb, NN * DD / 4);
  cvt4_kernel<<<256, 256, 0, stream>>>((const float4*)W, (ushort4*)Wb, DD * DD / 4);
  // Wh = h @ W^T
  gemm_wh<<<dim3(DD / 128, NN / 128), 256, 0, stream>>>(hb, Wb, DD, DD, Wh);
  rownorm_kernel<<<NN, 64, 0, stream>>>(Wh, invn, den);
  u_wht_kernel<<<dim3(NN / 64, DD / 64), 256, 0, stream>>>(Wh, invn, U, WhT);
  // fused: S -> exp/mask -> P(LDS) -> PV, fp32 partials per j-half + den atomics
  flash<<<dim3(2, NN / 64), 512, 0, stream>>>(U, WhT, adj, acc0, den);
  // out = (acc0 + acc1) / den
  reduce2_kernel<<<NN * DD / 4 / 256, 256, 0, stream>>>(
      (const float4*)acc0, (const float4*)acc1, den, (float4*)out);
}

// Round 7
// 568.751 us; speedup vs baseline: 2.1248x; 2.1248x over previous
//
#include <hip/hip_runtime.h>
#include <hip/hip_bf16.h>
#include <stdint.h>

#define NN 8192
#define DD 512

typedef unsigned short u16;
typedef __attribute__((ext_vector_type(8))) short short8;
typedef __attribute__((ext_vector_type(4))) float f32x4;

// async global->LDS, 16B per lane; LDS dest = wave-uniform base + lane*16
__device__ __forceinline__ void gld_lds16(const void* g, void* l) {
  __builtin_amdgcn_global_load_lds(
      (const __attribute__((address_space(1))) uint32_t*)(uintptr_t)g,
      (__attribute__((address_space(3))) uint32_t*)(uintptr_t)l,
      16, 0, 0);
}

__device__ __forceinline__ u16 f2bf(float f) {
  __hip_bfloat16 b = __float2bfloat16(f);
  return __builtin_bit_cast(u16, b);
}

__global__ void fill_kernel(float* __restrict__ p, int n, float v) {
  int i = blockIdx.x * 256 + threadIdx.x;
  int stride = gridDim.x * 256;
  for (; i < n; i += stride) p[i] = v;
}

__global__ void cvt4_kernel(const float4* __restrict__ src, ushort4* __restrict__ dst, int n4) {
  int i = blockIdx.x * 256 + threadIdx.x;
  int stride = gridDim.x * 256;
  for (; i < n4; i += stride) {
    float4 v = src[i];
    ushort4 o;
    o.x = f2bf(v.x); o.y = f2bf(v.y); o.z = f2bf(v.z); o.w = f2bf(v.w);
    dst[i] = o;
  }
}

// one wave per row: 1/||Wh_i||; also zeroes den[row]
__global__ void rownorm_kernel(const float* __restrict__ Wh, float* __restrict__ invn,
                               float* __restrict__ den) {
  int row = blockIdx.x;
  int l = threadIdx.x;  // 64
  const float4* p = (const float4*)(Wh + (size_t)row * DD);
  float4 a = p[l], b = p[l + 64];
  float s = a.x*a.x + a.y*a.y + a.z*a.z + a.w*a.w
          + b.x*b.x + b.y*b.y + b.z*b.z + b.w*b.w;
  #pragma unroll
  for (int off = 32; off; off >>= 1) s += __shfl_down(s, off);
  if (l == 0) {
    invn[row] = 1.0f / sqrtf(s);
    den[row] = 0.0f;
  }
}

// 64x64 tile: U = bf16(Wh * invn) (row-major) and WhT = bf16(Wh)^T
__global__ void u_wht_kernel(const float* __restrict__ Wh, const float* __restrict__ invn,
                             u16* __restrict__ U, u16* __restrict__ WhT) {
  __shared__ float tile[64][65];
  int i0 = blockIdx.x * 64, d0 = blockIdx.y * 64;
  int c = threadIdx.x & 63, rb = threadIdx.x >> 6;
  #pragma unroll
  for (int r = rb; r < 64; r += 4) {
    float v = Wh[(size_t)(i0 + r) * DD + d0 + c];
    tile[r][c] = v;
    U[(size_t)(i0 + r) * DD + d0 + c] = f2bf(v * invn[i0 + r]);
  }
  __syncthreads();
  #pragma unroll
  for (int r = rb; r < 64; r += 4) {
    WhT[(size_t)(d0 + r) * NN + i0 + c] = f2bf(tile[c][r]);
  }
}

// Wh-GEMM: C = A * B^T fp32, A:[M x K], B:[Nn x K] bf16. 128x128 tile, 256 thr.
__global__ void __launch_bounds__(256) gemm_wh(
    const u16* __restrict__ A, const u16* __restrict__ B,
    int Nn, int K, float* __restrict__ Cf)
{
  __shared__ __align__(16) u16 As[128 * 32];
  __shared__ __align__(16) u16 Bs[128 * 32];

  const int tid = threadIdx.x;
  const int w = tid >> 6;
  const int lane = tid & 63;
  const int lm = lane & 15;
  const int q = lane >> 4;
  const int row0 = blockIdx.y * 128;
  const int col0 = blockIdx.x * 128;
  const int RM = (w >> 1) * 64;
  const int RN = (w & 1) * 64;
  const int sr = tid >> 2;
  const int sk = (tid & 3) * 8;

  f32x4 acc[4][4];
  #pragma unroll
  for (int a_ = 0; a_ < 4; a_++)
    #pragma unroll
    for (int b_ = 0; b_ < 4; b_++)
      acc[a_][b_] = (f32x4){0.f, 0.f, 0.f, 0.f};

  const size_t Abase = (size_t)row0 * K;
  const size_t Bbase = (size_t)col0 * K;

  for (int k0 = 0; k0 < K; k0 += 32) {
    __syncthreads();
    gld_lds16(A + Abase + (size_t)sr * K + k0 + sk,        (char*)As + w * 1024);
    gld_lds16(A + Abase + (size_t)(sr + 64) * K + k0 + sk, (char*)As + 4096 + w * 1024);
    gld_lds16(B + Bbase + (size_t)sr * K + k0 + sk,        (char*)Bs + w * 1024);
    gld_lds16(B + Bbase + (size_t)(sr + 64) * K + k0 + sk, (char*)Bs + 4096 + w * 1024);
    __syncthreads();

    short8 af[4], bfr[4];
    #pragma unroll
    for (int mt = 0; mt < 4; mt++)
      af[mt] = *(const short8*)&As[(RM + mt * 16 + lm) * 32 + q * 8];
    #pragma unroll
    for (int nt = 0; nt < 4; nt++)
      bfr[nt] = *(const short8*)&Bs[(RN + nt * 16 + lm) * 32 + q * 8];

    #pragma unroll
    for (int mt = 0; mt < 4; mt++)
      #pragma unroll
      for (int nt = 0; nt < 4; nt++)
        acc[mt][nt] = __builtin_amdgcn_mfma_f32_16x16x32_bf16(af[mt], bfr[nt], acc[mt][nt], 0, 0, 0);
  }

  #pragma unroll
  for (int mt = 0; mt < 4; mt++) {
    const int ib = row0 + RM + mt * 16 + q * 4;
    #pragma unroll
    for (int rr = 0; rr < 4; rr++) {
      const int i = ib + rr;
      #pragma unroll
      for (int nt = 0; nt < 4; nt++) {
        const int jc = col0 + RN + nt * 16 + lm;
        Cf[(size_t)i * Nn + jc] = acc[mt][nt][rr];
      }
    }
  }
}

// sim-GEMM v6: v4 (full 64x64 grid, 128^2 tile, 4 waves) with a 4-DEEP BUFFER
// RING instead of double-buffer. Theory: v3/v4/v5 all plateau at 180-190us with
// no pipe >28% because the dbuf caps prefetch lead at ~1.5 tiles (~300-500cyc)
// vs ~200-900cyc U-panel load latency -> every tile stalls at the vmcnt. The
// ring stages tile T+4 into the buffer consumed at tile T; steady-state
// vmcnt(12) leaves T+1..T+3's 12 loads in flight (T+1 complete) -> lead ~3.5
// tiles. 64 KB LDS still fits 2 blocks/CU. Same loads, same MFMA order, same
// epilogue as v4 -> bit-identical output.
__global__ void __launch_bounds__(256, 2) gemm_sim(
    const u16* __restrict__ U, const int* __restrict__ adj,
    u16* __restrict__ Pb, float* __restrict__ den)
{
  __shared__ __align__(16) char lds[65536];  // ring buf b at b*16384: A 8KB | B 8KB

  const int bj = blockIdx.x;
  const int bi = blockIdx.y;

  const int tid = threadIdx.x;
  const int w = tid >> 6;
  const int lane = tid & 63;
  const int lm = lane & 15;
  const int q = lane >> 4;
  const int row0 = bi * 128;
  const int col0 = bj * 128;
  const int RM = (w >> 1) * 64;
  const int RN = (w & 1) * 64;
  const bool diag = (bi == bj);

  const u16* Ab = U + (size_t)row0 * DD;
  const u16* Bb = U + (size_t)col0 * DD;

  // staging: 256 threads cover 64 rows per gld (row tid>>2, slot tid&3);
  // source content chunk = slot ^ ((row>>1)&3)  (row>>1 == tid>>3)
  const int srow = tid >> 2;                                  // 0..63
  const int sch8 = (((tid & 3) ^ ((tid >> 3) & 3)) << 3);     // element offset
  const int wofs = w << 10;                                   // per-wave LDS base

  // read-side: logical (r, chunk c) lives at byte r*64 + ((c ^ ((r>>1)&3))<<4);
  // (r>>1)&3 invariant under r += 16, fold once.
  const int rA = RM + lm;
  const int rB = RN + lm;
  const int aoff = rA * 64 + ((q ^ ((rA >> 1) & 3)) << 4);
  const int boff = 8192 + rB * 64 + ((q ^ ((rB >> 1) & 3)) << 4);

  f32x4 acc[4][4];
  #pragma unroll
  for (int a_ = 0; a_ < 4; a_++)
    #pragma unroll
    for (int b_ = 0; b_ < 4; b_++)
      acc[a_][b_] = (f32x4){0.f, 0.f, 0.f, 0.f};

  // ---- adj prefetch: batch mt=0 issued FIRST (oldest VMEM ops). Prologue
  // vmcnt(12) waits for {16 adj + tile0's 4 stages}, leaving tiles 1..3's 12
  // in flight -- adj latency fully hidden under the K-loop.
  int na0[4][4], na1[4][4];
  {
    const int ib0 = row0 + RM + q * 4;
    #pragma unroll
    for (int rr = 0; rr < 4; rr++)
      #pragma unroll
      for (int nt = 0; nt < 4; nt++)
        na0[rr][nt] = adj[(size_t)(ib0 + rr) * NN + col0 + RN + nt * 16 + lm];
  }
  asm volatile("" ::: "memory");  // pin adj loads before the staging stream

#define SSTAGE(koff, dstoff)                                                      \
  do {                                                                            \
    char* d_ = lds + (dstoff);                                                    \
    gld_lds16(Ab + (size_t)srow * DD + (koff) + sch8,        d_ + wofs);          \
    gld_lds16(Ab + (size_t)(srow + 64) * DD + (koff) + sch8, d_ + 4096 + wofs);   \
    gld_lds16(Bb + (size_t)srow * DD + (koff) + sch8,        d_ + 8192 + wofs);   \
    gld_lds16(Bb + (size_t)(srow + 64) * DD + (koff) + sch8, d_ + 12288 + wofs);  \
  } while (0)

  // prologue: tiles 0..3 -> ring bufs 0..3; drain adj + tile0, leave 12 in flight
  SSTAGE(0, 0);
  SSTAGE(32, 16384);
  SSTAGE(64, 32768);
  SSTAGE(96, 49152);
  asm volatile("s_waitcnt vmcnt(12)" ::: "memory");
  asm volatile("s_barrier" ::: "memory");

  // Per tile T (buffer CBOFF = (T&3)*16384):
  //  reads(T) -> bar -> lgkm0 -> MFMA half1 -> bar -> stage(T+4 -> same buf)
  //  -> bar -> MFMA half2 -> vmcnt(VMC: T+1 complete) -> bar
#define STILE(T, CBOFF, DOSTAGE, VMC)                                             \
  do {                                                                            \
    const char* cb = lds + (CBOFF);                                               \
    short8 af[4], bfr[4];                                                         \
    _Pragma("unroll")                                                             \
    for (int m = 0; m < 4; m++)                                                   \
      af[m] = *(const short8*)(cb + aoff + m * 1024);                             \
    _Pragma("unroll")                                                             \
    for (int n = 0; n < 4; n++)                                                   \
      bfr[n] = *(const short8*)(cb + boff + n * 1024);                            \
    asm volatile("s_barrier" ::: "memory");                                       \
    asm volatile("s_waitcnt lgkmcnt(0)" ::: "memory");                            \
    __builtin_amdgcn_s_setprio(1);                                                \
    _Pragma("unroll")                                                             \
    for (int m = 0; m < 2; m++)                                                   \
      _Pragma("unroll")                                                           \
      for (int n = 0; n < 4; n++)                                                 \
        acc[m][n] = __builtin_amdgcn_mfma_f32_16x16x32_bf16(af[m], bfr[n], acc[m][n], 0, 0, 0); \
    __builtin_amdgcn_s_setprio(0);                                                \
    asm volatile("s_barrier" ::: "memory");                                       \
    if (DOSTAGE) SSTAGE(((T) + 4) * 32, (CBOFF));                                 \
    asm volatile("s_barrier" ::: "memory");                                       \
    __builtin_amdgcn_s_setprio(1);                                                \
    _Pragma("unroll")                                                             \
    for (int m = 2; m < 4; m++)                                                   \
      _Pragma("unroll")                                                           \
      for (int n = 0; n < 4; n++)                                                 \
        acc[m][n] = __builtin_amdgcn_mfma_f32_16x16x32_bf16(af[m], bfr[n], acc[m][n], 0, 0, 0); \
    __builtin_amdgcn_s_setprio(0);                                                \
    asm volatile("s_waitcnt " VMC ::: "memory");                                  \
    asm volatile("s_barrier" ::: "memory");                                       \
  } while (0)

  #pragma unroll 1
  for (int t = 0; t < 12; t += 4) {
    STILE(t + 0, 0,     1, "vmcnt(12)");
    STILE(t + 1, 16384, 1, "vmcnt(12)");
    STILE(t + 2, 32768, 1, "vmcnt(12)");
    STILE(t + 3, 49152, 1, "vmcnt(12)");
  }
  // drain ramp: outstanding stages {13,14,15} -> {14,15} -> {15} -> {}
  STILE(12, 0,     0, "vmcnt(8)");
  STILE(13, 16384, 0, "vmcnt(4)");
  STILE(14, 32768, 0, "vmcnt(0)");
  STILE(15, 49152, 0, "vmcnt(0)");
#undef STILE
#undef SSTAGE

  // ---- epilogue: C/D layout col = lm, row = q*4 + rr. adj batches pipelined
  // 1-deep: issue batch MT+1's loads, then process batch MT from registers.
#define EPI(MT, NAC, NAN, DOLOAD)                                                 \
  do {                                                                            \
    if (DOLOAD) {                                                                 \
      const int ibn = row0 + RM + ((MT) + 1) * 16 + q * 4;                        \
      _Pragma("unroll")                                                           \
      for (int rr = 0; rr < 4; rr++)                                              \
        _Pragma("unroll")                                                         \
        for (int nt = 0; nt < 4; nt++)                                            \
          NAN[rr][nt] = adj[(size_t)(ibn + rr) * NN + col0 + RN + nt * 16 + lm];  \
    }                                                                             \
    const int ibc = row0 + RM + (MT) * 16 + q * 4;                                \
    _Pragma("unroll")                                                             \
    for (int rr = 0; rr < 4; rr++) {                                              \
      const int i = ibc + rr;                                                     \
      float psum = 0.f;                                                           \
      _Pragma("unroll")                                                           \
      for (int nt = 0; nt < 4; nt++) {                                            \
        const int jc = col0 + RN + nt * 16 + lm;                                  \
        const float ev = __expf(acc[MT][nt][rr]);                                 \
        const bool on = (NAC[rr][nt] != 0) || (diag && i == jc);                  \
        const float p = on ? ev : 0.0f;                                           \
        psum += p;                                                                \
        Pb[(size_t)i * NN + jc] = f2bf(p);                                        \
      }                                                                           \
      _Pragma("unroll")                                                           \
      for (int off = 8; off; off >>= 1) psum += __shfl_down(psum, off, 16);       \
      if (lm == 0) atomicAdd(&den[i], psum);                                      \
    }                                                                             \
  } while (0)

  EPI(0, na0, na1, 1);
  EPI(1, na1, na0, 1);
  EPI(2, na0, na1, 1);
  EPI(3, na1, na0, 0);
#undef EPI
}

// out-GEMM v2: 256x256 tile, BK=32, 8 waves (2M x 4N), split-K=4 via blockIdx.z.
// Phase-split schedule: counted s_waitcnt vmcnt(4), XOR chunk swizzle both-sides,
// setprio around MFMA clusters. 64 KB LDS double-buffer.
__global__ void __launch_bounds__(512, 2) gemm_out2(
    const u16* __restrict__ P_,   // P [NN x NN]
    const u16* __restrict__ Wt,   // WhT [DD x NN]
    u16* __restrict__ p0, u16* __restrict__ p1,
    u16* __restrict__ p2, u16* __restrict__ p3)
{
  __shared__ __align__(16) char lds[65536];  // buf b at b*32768: A 16KB | B 16KB

  const int tid = threadIdx.x;
  const int lane = tid & 63;
  const int lm = lane & 15;
  const int q = lane >> 4;
  const int w = tid >> 6;       // 0..7
  const int wm = w >> 2;        // 0..1 -> 128 rows
  const int wn = w & 3;         // 0..3 -> 64 cols
  const int row0 = blockIdx.x * 256;   // i block
  const int col0 = blockIdx.y * 256;   // d block
  const int z = blockIdx.z;            // split-K
  const int kBegin = z * (NN / 4);
  const int NT = (NN / 4) / 32;        // 64 K-tiles

  const u16* Ab = P_ + (size_t)row0 * NN;
  const u16* Bb = Wt + (size_t)col0 * NN;

  const int srow = tid >> 2;                                  // 0..127
  const int sch8 = (((tid & 3) ^ ((tid >> 3) & 3)) << 3);     // element offset
  const int wofs = (tid >> 6) << 10;                          // per-wave LDS base

  const int rA = wm * 128 + lm;
  const int rB = wn * 64 + lm;
  const int aoff = rA * 64 + ((q ^ ((rA >> 1) & 3)) << 4);
  const int boff = 16384 + rB * 64 + ((q ^ ((rB >> 1) & 3)) << 4);

  f32x4 acc[8][4];
  #pragma unroll
  for (int m = 0; m < 8; m++)
    #pragma unroll
    for (int n = 0; n < 4; n++)
      acc[m][n] = (f32x4){0.f, 0.f, 0.f, 0.f};

#define STAGE4(koff, dstoff)                                                      \
  do {                                                                            \
    char* d_ = lds + (dstoff);                                                    \
    gld_lds16(Ab + (size_t)srow * NN + (koff) + sch8,         d_ + wofs);         \
    gld_lds16(Ab + (size_t)(srow + 128) * NN + (koff) + sch8, d_ + 8192 + wofs);  \
    gld_lds16(Bb + (size_t)srow * NN + (koff) + sch8,         d_ + 16384 + wofs); \
    gld_lds16(Bb + (size_t)(srow + 128) * NN + (koff) + sch8, d_ + 24576 + wofs); \
  } while (0)

  STAGE4(kBegin, 0);
  STAGE4(kBegin + 32, 32768);
  asm volatile("s_waitcnt vmcnt(4)" ::: "memory");
  asm volatile("s_barrier" ::: "memory");

#define TILE(T, CBOFF)                                                            \
  do {                                                                            \
    const char* cb = lds + (CBOFF);                                               \
    short8 af[8], bf_[4];                                                         \
    _Pragma("unroll")                                                             \
    for (int m = 0; m < 8; m++)                                                   \
      af[m] = *(const short8*)(cb + aoff + m * 1024);                             \
    _Pragma("unroll")                                                             \
    for (int n = 0; n < 4; n++)                                                   \
      bf_[n] = *(const short8*)(cb + boff + n * 1024);                            \
    asm volatile("s_barrier" ::: "memory");                                       \
    asm volatile("s_waitcnt lgkmcnt(0)" ::: "memory");                            \
    __builtin_amdgcn_s_setprio(1);                                                \
    _Pragma("unroll")                                                             \
    for (int m = 0; m < 4; m++)                                                   \
      _Pragma("unroll")                                                           \
      for (int n = 0; n < 4; n++)                                                 \
        acc[m][n] = __builtin_amdgcn_mfma_f32_16x16x32_bf16(af[m], bf_[n], acc[m][n], 0, 0, 0); \
    __builtin_amdgcn_s_setprio(0);                                                \
    asm volatile("s_barrier" ::: "memory");                                       \
    if ((T) + 2 < NT) STAGE4(kBegin + ((T) + 2) * 32, CBOFF);                     \
    asm volatile("s_barrier" ::: "memory");                                       \
    __builtin_amdgcn_s_setprio(1);                                                \
    _Pragma("unroll")                                                             \
    for (int m = 4; m < 8; m++)                                                   \
      _Pragma("unroll")                                                           \
      for (int n = 0; n < 4; n++)                                                 \
        acc[m][n] = __builtin_amdgcn_mfma_f32_16x16x32_bf16(af[m], bf_[n], acc[m][n], 0, 0, 0); \
    __builtin_amdgcn_s_setprio(0);                                                \
    if ((T) + 2 < NT) { asm volatile("s_waitcnt vmcnt(4)" ::: "memory"); }        \
    else              { asm volatile("s_waitcnt vmcnt(0)" ::: "memory"); }        \
    asm volatile("s_barrier" ::: "memory");                                       \
  } while (0)

  #pragma unroll 1
  for (int t = 0; t < NT; t += 2) {
    TILE(t, 0);
    TILE(t + 1, 32768);
  }
#undef TILE
#undef STAGE4

  u16* const part = (z == 0) ? p0 : (z == 1) ? p1 : (z == 2) ? p2 : p3;
  #pragma unroll
  for (int m = 0; m < 8; m++) {
    const int ib = row0 + wm * 128 + m * 16 + q * 4;
    #pragma unroll
    for (int rr = 0; rr < 4; rr++) {
      const int i = ib + rr;
      #pragma unroll
      for (int n = 0; n < 4; n++) {
        const int dc = col0 + wn * 64 + n * 16 + lm;
        part[(size_t)i * DD + dc] = f2bf(acc[m][n][rr]);
      }
    }
  }
}

// out = (sum of 4 bf16 partials) / den[row]; each thread handles 8 cols
__global__ void reduce4_kernel(const uint4* __restrict__ p0, const uint4* __restrict__ p1,
                               const uint4* __restrict__ p2, const uint4* __restrict__ p3,
                               const float* __restrict__ den, float4* __restrict__ out) {
  const int idx = blockIdx.x * 256 + threadIdx.x;   // NN*DD/8 units of 8 cols
  const int row = idx >> 6;                          // 64 units per row
  const float dinv = 1.0f / den[row];
  float s[8] = {0, 0, 0, 0, 0, 0, 0, 0};
  #pragma unroll
  for (int zp = 0; zp < 4; zp++) {
    const uint4 u = (zp == 0 ? p0 : zp == 1 ? p1 : zp == 2 ? p2 : p3)[idx];
    s[0] += __uint_as_float(u.x << 16); s[1] += __uint_as_float(u.x & 0xffff0000u);
    s[2] += __uint_as_float(u.y << 16); s[3] += __uint_as_float(u.y & 0xffff0000u);
    s[4] += __uint_as_float(u.z << 16); s[5] += __uint_as_float(u.z & 0xffff0000u);
    s[6] += __uint_as_float(u.w << 16); s[7] += __uint_as_float(u.w & 0xffff0000u);
  }
  float4 o0 = {s[0] * dinv, s[1] * dinv, s[2] * dinv, s[3] * dinv};
  float4 o1 = {s[4] * dinv, s[5] * dinv, s[6] * dinv, s[7] * dinv};
  out[idx * 2] = o0;
  out[idx * 2 + 1] = o1;
}

extern "C" void kernel_launch(void* const* d_in, const int* in_sizes, int n_in,
                              void* d_out, int out_size, void* d_ws, size_t ws_size,
                              hipStream_t stream) {
  const float* h = (const float*)d_in[0];
  const int* adj = (const int*)d_in[1];
  const float* W = (const float*)d_in[2];
  float* out = (float*)d_out;

  const size_t SZ_P    = (size_t)NN * NN * 2;      // 134.2 MB
  const size_t SZ_X0   = (size_t)NN * NN / 8;      // 8.4 MB  (-> part0)
  const size_t SZ_WHT  = (size_t)DD * NN * 2;      // 8.4 MB
  const size_t SZ_HB   = (size_t)NN * DD * 2;      // 8.4 MB  (-> part2)
  const size_t SZ_WB   = (size_t)DD * DD * 2;      // 0.5 MB
  const size_t SZ_U    = (size_t)NN * DD * 2;      // 8.4 MB  (-> part1)
  const size_t SZ_P3   = (size_t)NN * DD * 2;      // 8.4 MB  (part3)
  const size_t NEEDED  = SZ_P + SZ_X0 + SZ_WHT + SZ_HB + SZ_WB + SZ_U + SZ_P3 + 2 * (size_t)NN * 4;

  if (ws_size < NEEDED) {
    fill_kernel<<<256, 256, 0, stream>>>(out, out_size, 12345.0f);
    return;
  }

  char* ws = (char*)d_ws;
  size_t off = 0;
  u16*   P    = (u16*)(ws + off); off += SZ_P;
  u16*   x0   = (u16*)(ws + off); off += SZ_X0;
  u16*   WhT  = (u16*)(ws + off); off += SZ_WHT;
  u16*   hb   = (u16*)(ws + off); off += SZ_HB;
  u16*   Wb   = (u16*)(ws + off); off += SZ_WB;
  u16*   U    = (u16*)(ws + off); off += SZ_U;
  u16*   p3   = (u16*)(ws + off); off += SZ_P3;
  float* invn = (float*)(ws + off);
  float* den  = invn + NN;

  // Wh fp32 (16.8 MB) aliases the P prefix: dead before sim writes P.
  float* Wh = (float*)P;
  // split-K partials reuse regions dead after the sim-GEMM:
  u16* part0 = x0;
  u16* part1 = U;
  u16* part2 = hb;
  u16* part3 = p3;

  cvt4_kernel<<<1024, 256, 0, stream>>>((const float4*)h, (ushort4*)hb, NN * DD / 4);
  cvt4_kernel<<<256, 256, 0, stream>>>((const float4*)W, (ushort4*)Wb, DD * DD / 4);
  // Wh = h @ W^T
  gemm_wh<<<dim3(DD / 128, NN / 128), 256, 0, stream>>>(hb, Wb, DD, DD, Wh);
  rownorm_kernel<<<NN, 64, 0, stream>>>(Wh, invn, den);
  u_wht_kernel<<<dim3(NN / 64, DD / 64), 256, 0, stream>>>(Wh, invn, U, WhT);
  // P = mask ? exp(U U^T) : 0 (bf16), full grid, 4-deep ring prefetch, fused den
  gemm_sim<<<dim3(NN / 128, NN / 128), 256, 0, stream>>>(U, adj, P, den);
  // out partials: 256x256 tile, phase-split counted-vmcnt schedule, split-K=4
  gemm_out2<<<dim3(NN / 256, DD / 256, 4), 512, 0, stream>>>(P, WhT, part0, part1, part2, part3);
  // out = (p0+p1+p2+p3) / den
  reduce4_kernel<<<NN * DD / 8 / 256, 256, 0, stream>>>(
      (const uint4*)part0, (const uint4*)part1, (const uint4*)part2, (const uint4*)part3,
      den, (float4*)out);
}